// Round 12
// baseline (59.113 us; speedup 1.0000x reference)
//
#include <hip/hip_runtime.h>

// GraphUpSamplingLayer: 3-D k=1 NN argmin + batched feature gather.
// B=4, C=512, M=2048 (coarse points), N=8192 (dense points), D=3.
//
// ROUND 12 = GATHER MEASUREMENT. Corrected accounting (profiled = 0.80x
// timed clock, validated via R9/R10 cross-check): argmin v8 = 12.3us (near
// floor), gather = 20.1us = 53% of copy ceiling <- the real target.
// gather_probe4 stages once then runs the gather loop 4x (idempotent d_out
// rewrites): one ~100us profiled dispatch -> top-5 visible with counters;
// timed (T - 32.33)/3 = pure gather-loop marginal cost.
constexpr int B = 4;
constexpr int C = 512;
constexpr int M = 2048;
constexpr int N = 8192;

// ---------------------------------------------------------------------------
// v8 argmin (unchanged; 12.3us timed, best of 9 structures).
// ---------------------------------------------------------------------------
__global__ __launch_bounds__(512) void nn_argmin_v8(
    const float* __restrict__ pos,      // [B][N][3]
    const float* __restrict__ sub_pos,  // [B][M][3]
    int* __restrict__ idx_out)          // [B][N]
{
    __shared__ float4 sp[M];                   // 32 KB: (x, y, z, ||s||^2/2)
    __shared__ unsigned long long red[8][64];  // 4 KB

    const int b  = blockIdx.x >> 7;            // 128 blocks per batch
    const int n0 = (blockIdx.x & 127) << 6;    // 64 queries per block
    const int t  = threadIdx.x;
    const int w    = t >> 6;                   // wave 0..7
    const int lane = t & 63;

    const float* spb = sub_pos + (size_t)b * (M * 3);
    for (int i = t; i < M; i += 512) {
        const float x = spb[i * 3 + 0];
        const float y = spb[i * 3 + 1];
        const float z = spb[i * 3 + 2];
        sp[i] = make_float4(x, y, z, 0.5f * fmaf(z, z, fmaf(y, y, x * x)));
    }
    __syncthreads();

    const int n = n0 + lane;
    const float* pp = pos + ((size_t)b * N + n) * 3;
    const float px = pp[0], py = pp[1], pz = pp[2];

    float best = 1e30f;
    int bm = 0;
    const int m0 = w << 8;                     // this wave's 256-candidate slice
    float4 c = sp[m0];                         // 1-deep uniform prefetch
    #pragma unroll 8
    for (int j = 0; j < 256; ++j) {
        const float4 cc = c;
        c = sp[m0 + ((j + 1) & 255)];
        float s = fmaf(-cc.x, px, cc.w);
        s = fmaf(-cc.y, py, s);
        s = fmaf(-cc.z, pz, s);
        const bool lt = s < best;              // strict <: first index in slice
        best = lt ? s : best;
        bm   = lt ? (m0 + j) : bm;
    }

    unsigned int fb = __float_as_uint(best);   // order-preserving key (neg ok)
    fb ^= (unsigned int)((int)fb >> 31) | 0x80000000u;
    red[w][lane] = ((unsigned long long)fb << 32) | (unsigned int)bm;
    __syncthreads();

    if (w == 0) {
        unsigned long long k = red[0][lane];
        #pragma unroll
        for (int ww = 1; ww < 8; ++ww) {
            const unsigned long long o = red[ww][lane];
            k = (o < k) ? o : k;
        }
        idx_out[(size_t)b * N + n] = (int)(unsigned int)k;
    }
}

// ---------------------------------------------------------------------------
// gather_probe4: stage row once, then 4 IDEMPOTENT reps of the gather loop
// (identical values to d_out each rep). Rep 1 = the real gather; reps 2-4
// make this dispatch ~100us profiled (top-5 visible -> counters) and give
// the timed marginal loop cost. Same output as a single gather.
// ---------------------------------------------------------------------------
__global__ __launch_bounds__(256) void gather_probe4(
    const float* __restrict__ sub_x,  // [B][C][M]
    const int* __restrict__ idx,      // [B][N]
    float* __restrict__ out)          // [B][C][N]
{
    __shared__ float row[M];          // 8 KB

    const int b = blockIdx.x >> 9;    // C = 512
    const int c = blockIdx.x & 511;
    const int t = threadIdx.x;

    const float* rsrc = sub_x + ((size_t)b * C + c) * M;
    for (int i = t; i < M; i += 256) row[i] = rsrc[i];
    __syncthreads();

    const int4* iv = (const int4*)(idx + (size_t)b * N);
    float4* ov = (float4*)(out + ((size_t)b * C + c) * N);
    for (int rep = 0; rep < 4; ++rep) {
        #pragma unroll
        for (int i = t; i < N / 4; i += 256) {
            const int4 ii = iv[i];
            float4 v;
            v.x = row[ii.x];
            v.y = row[ii.y];
            v.z = row[ii.z];
            v.w = row[ii.w];
            ov[i] = v;                // same value every rep: idempotent
        }
        __syncthreads();              // keep reps distinct in time
    }
}

extern "C" void kernel_launch(void* const* d_in, const int* in_sizes, int n_in,
                              void* d_out, int out_size, void* d_ws, size_t ws_size,
                              hipStream_t stream) {
    const float* sub_x   = (const float*)d_in[0];  // [B][C][M]
    const float* sub_pos = (const float*)d_in[1];  // [B][M][3]
    const float* pos     = (const float*)d_in[2];  // [B][N][3]
    float* out = (float*)d_out;                    // [B][C][N]
    int* idx = (int*)d_ws;                         // B*N*4 = 128 KB scratch

    nn_argmin_v8<<<B * (N / 64), 512, 0, stream>>>(pos, sub_pos, idx);
    gather_probe4<<<B * C, 256, 0, stream>>>(sub_x, idx, out);
}

// Round 13
// 32.224 us; speedup vs baseline: 1.8344x; 1.8344x over previous
//
#include <hip/hip_runtime.h>

// GraphUpSamplingLayer: 3-D k=1 NN argmin + batched feature gather.
// B=4, C=512, M=2048 (coarse points), N=8192 (dense points), D=3.
//
// R12 full re-fit (timed-only accounting, all 12 rounds consistent +-1us):
//   fixed replay/launch overhead ~12us, gather 9.7us (write-roofline),
//   argmin v8 10.7us (LDS-broadcast-issue ~4096 reads/CU + VALU 6.8us).
// v10 = v8 structure with Qpl=2: halves broadcast reads/CU (2048 ~ 4.7us).
constexpr int B = 4;
constexpr int C = 512;
constexpr int M = 2048;
constexpr int N = 8192;

// ---------------------------------------------------------------------------
// v10 argmin: query-pair-per-lane, candidate-slice-per-wave, broadcast LDS.
// Block = 1024 thr = 16 waves; block owns 128 queries (lane l owns n0+l and
// n0+64+l); wave w scans slice [128w, 128w+128) via uniform-address
// ds_read_b128 broadcast, 1-deep prefetch. Per candidate per query:
// 3 fma + cmp + 2 cndmask (score = ||s||^2/2 - p.s, h staged in float4.w;
// absmax 0.0 across R7-R12). Grid 256 blocks = 1 block/CU = 4 waves/SIMD.
// Cross-wave merge: packed u64 (monotonic-key(d)<<32 | m) min; key is the
// order-preserving float->u32 map (scores can be negative).
// Tie-break = jnp.argmin first-occurrence: in-slice m-ascending strict <;
// equal keys across slices -> smaller m via low word.
// ---------------------------------------------------------------------------
__global__ __launch_bounds__(1024) void nn_argmin_v10(
    const float* __restrict__ pos,      // [B][N][3]
    const float* __restrict__ sub_pos,  // [B][M][3]
    int* __restrict__ idx_out)          // [B][N]
{
    __shared__ float4 sp[M];                       // 32 KB: (x,y,z,||s||^2/2)
    __shared__ unsigned long long red[2][16][64];  // 16 KB

    const int b  = blockIdx.x >> 6;                // 64 blocks per batch
    const int n0 = (blockIdx.x & 63) << 7;         // 128 queries per block
    const int t  = threadIdx.x;
    const int w    = t >> 6;                       // wave 0..15
    const int lane = t & 63;

    const float* spb = sub_pos + (size_t)b * (M * 3);
    #pragma unroll
    for (int i = t; i < M; i += 1024) {
        const float x = spb[i * 3 + 0];
        const float y = spb[i * 3 + 1];
        const float z = spb[i * 3 + 2];
        sp[i] = make_float4(x, y, z, 0.5f * fmaf(z, z, fmaf(y, y, x * x)));
    }
    __syncthreads();

    // Two queries per lane: n0+lane and n0+64+lane.
    const float* p0 = pos + ((size_t)b * N + n0 + lane) * 3;
    const float* p1 = p0 + 64 * 3;
    const float px0 = p0[0], py0 = p0[1], pz0 = p0[2];
    const float px1 = p1[0], py1 = p1[1], pz1 = p1[2];

    float best0 = 1e30f, best1 = 1e30f;
    int   bm0 = 0,       bm1 = 0;
    const int m0 = w << 7;                         // this wave's 128-cand slice
    float4 c = sp[m0];                             // 1-deep uniform prefetch
    #pragma unroll 8
    for (int j = 0; j < 128; ++j) {
        const float4 cc = c;
        c = sp[m0 + ((j + 1) & 127)];
        const int m = m0 + j;
        float s = fmaf(-cc.x, px0, cc.w);
        s = fmaf(-cc.y, py0, s);
        s = fmaf(-cc.z, pz0, s);
        const bool lt0 = s < best0;                // strict <: first index
        best0 = lt0 ? s : best0;
        bm0   = lt0 ? m : bm0;
        float u = fmaf(-cc.x, px1, cc.w);
        u = fmaf(-cc.y, py1, u);
        u = fmaf(-cc.z, pz1, u);
        const bool lt1 = u < best1;
        best1 = lt1 ? u : best1;
        bm1   = lt1 ? m : bm1;
    }

    // Order-preserving float->u32 keys (scores can be negative).
    unsigned int f0 = __float_as_uint(best0);
    f0 ^= (unsigned int)((int)f0 >> 31) | 0x80000000u;
    unsigned int f1 = __float_as_uint(best1);
    f1 ^= (unsigned int)((int)f1 >> 31) | 0x80000000u;
    red[0][w][lane] = ((unsigned long long)f0 << 32) | (unsigned int)bm0;
    red[1][w][lane] = ((unsigned long long)f1 << 32) | (unsigned int)bm1;
    __syncthreads();

    if (w < 2) {                                   // wave w reduces query set w
        unsigned long long k = red[w][0][lane];
        #pragma unroll
        for (int ww = 1; ww < 16; ++ww) {
            const unsigned long long o = red[w][ww][lane];
            k = (o < k) ? o : k;
        }
        idx_out[(size_t)b * N + n0 + (w << 6) + lane] = (int)(unsigned int)k;
    }
}

// ---------------------------------------------------------------------------
// Phase 2: out[b][c][n] = sub_x[b][c][idx[b][n]]
// R12-measured: 8.93us/rep marginal = 7.2 TB/s effective write BW --
// at/above the 6.3 TB/s copy ceiling. Conflicts 8% of LDS reads, VALUBusy
// 3.7%: pure write-bound. Unchanged.
// ---------------------------------------------------------------------------
__global__ __launch_bounds__(256) void gather_kernel(
    const float* __restrict__ sub_x,  // [B][C][M]
    const int* __restrict__ idx,      // [B][N]
    float* __restrict__ out)          // [B][C][N]
{
    __shared__ float row[M];          // 8 KB

    const int b = blockIdx.x >> 9;    // C = 512
    const int c = blockIdx.x & 511;
    const int t = threadIdx.x;

    const float* rsrc = sub_x + ((size_t)b * C + c) * M;
    for (int i = t; i < M; i += 256) row[i] = rsrc[i];
    __syncthreads();

    const int4* iv = (const int4*)(idx + (size_t)b * N);
    float4* ov = (float4*)(out + ((size_t)b * C + c) * N);
    #pragma unroll
    for (int i = t; i < N / 4; i += 256) {
        const int4 ii = iv[i];
        float4 v;
        v.x = row[ii.x];
        v.y = row[ii.y];
        v.z = row[ii.z];
        v.w = row[ii.w];
        ov[i] = v;
    }
}

extern "C" void kernel_launch(void* const* d_in, const int* in_sizes, int n_in,
                              void* d_out, int out_size, void* d_ws, size_t ws_size,
                              hipStream_t stream) {
    const float* sub_x   = (const float*)d_in[0];  // [B][C][M]
    const float* sub_pos = (const float*)d_in[1];  // [B][M][3]
    const float* pos     = (const float*)d_in[2];  // [B][N][3]
    float* out = (float*)d_out;                    // [B][C][N]
    int* idx = (int*)d_ws;                         // B*N*4 = 128 KB scratch

    nn_argmin_v10<<<B * (N / 128), 1024, 0, stream>>>(pos, sub_pos, idx);
    gather_kernel<<<B * C, 256, 0, stream>>>(sub_x, idx, out);
}